// Round 1
// baseline (492.216 us; speedup 1.0000x reference)
//
#include <hip/hip_runtime.h>
#include <hip/hip_fp16.h>

#define QLEN   65536
#define EDIM   256

typedef _Float16 half8 __attribute__((ext_vector_type(8)));
typedef float    f32x4 __attribute__((ext_vector_type(4)));

// ---------------- workspace layout (bytes) ----------------
// Wqkv f16 [768][256] | Wout f16 [256][256] | q f16 | k f16 | v f16 | attn f16
static const size_t WQKV_OFF = 0;
static const size_t WOUT_OFF = 768u * 256u * 2u;                 // 393216
static const size_t Q_OFF    = WOUT_OFF + 256u * 256u * 2u;      // 524288
static const size_t K_OFF    = Q_OFF + (size_t)QLEN * EDIM * 2u;
static const size_t V_OFF    = K_OFF + (size_t)QLEN * EDIM * 2u;
static const size_t A_OFF    = V_OFF + (size_t)QLEN * EDIM * 2u; // end ~134.7MB

// ---------------- weight f32 -> f16 conversion ----------------
__global__ void prep_weights(const float* __restrict__ wqkv,
                             const float* __restrict__ wout,
                             __half* __restrict__ dst)
{
  int g = (blockIdx.x * blockDim.x + threadIdx.x) * 4;
  float4 f;
  if (g < 768 * 256) f = *(const float4*)(wqkv + g);
  else               f = *(const float4*)(wout + (g - 768 * 256));
  union { __half h[4]; uint2 u; } c;
  c.h[0] = __float2half(f.x); c.h[1] = __float2half(f.y);
  c.h[2] = __float2half(f.z); c.h[3] = __float2half(f.w);
  *(uint2*)(dst + g) = c.u;
}

// ---------------- GEMM: Out[m][n] = (sum_k A[m][k]*W[n][k] + bias[n]) * scale ----
// M tiled by 128 (blockIdx.x), N=256 tiled by 128 (blockIdx.y), K=256.
// 4 waves in 2x2; each wave does a 64x64 region = 4x4 tiles of 16x16, BK=32.
template<bool A_F32, bool OUT_F16>
__global__ __launch_bounds__(256)
void gemm_e256(const void* __restrict__ Ain,
               const __half* __restrict__ W,     // [256][256] f16, row-major (n,k)
               const float* __restrict__ bias,   // [256]
               float scale,
               void* __restrict__ Outp)
{
  __shared__ __half As[128][40];   // pad 32->40 halfs (80B rows; 2-way banks = free)
  __shared__ __half Bs[128][40];
  const int tid  = threadIdx.x;
  const int lane = tid & 63;
  const int wid  = tid >> 6;
  const int wr   = wid >> 1, wc = wid & 1;
  const int gm   = blockIdx.x * 128;
  const int gn   = blockIdx.y * 128;

  f32x4 acc[4][4] = {};

  const int sr = tid >> 1;          // staging row 0..127
  const int sk = (tid & 1) * 16;    // staging k offset 0/16

  const int fr = lane & 15;         // fragment row/col within 16
  const int fo = (lane >> 4) * 8;   // fragment k offset

  for (int kc = 0; kc < 8; ++kc) {
    __syncthreads();
    if (A_F32) {
      const float* A   = (const float*)Ain;
      const float* src = A + (size_t)(gm + sr) * 256 + kc * 32 + sk;
      union { __half h[16]; uint4 u[2]; } t;
      #pragma unroll
      for (int u = 0; u < 4; ++u) {
        float4 f = ((const float4*)src)[u];
        t.h[u*4+0] = __float2half(f.x); t.h[u*4+1] = __float2half(f.y);
        t.h[u*4+2] = __float2half(f.z); t.h[u*4+3] = __float2half(f.w);
      }
      *(uint4*)&As[sr][sk]     = t.u[0];
      *(uint4*)&As[sr][sk + 8] = t.u[1];
    } else {
      const __half* A  = (const __half*)Ain;
      const uint4* src = (const uint4*)(A + (size_t)(gm + sr) * 256 + kc * 32 + sk);
      *(uint4*)&As[sr][sk]     = src[0];
      *(uint4*)&As[sr][sk + 8] = src[1];
    }
    {
      const uint4* src = (const uint4*)(W + (size_t)(gn + sr) * 256 + kc * 32 + sk);
      *(uint4*)&Bs[sr][sk]     = src[0];
      *(uint4*)&Bs[sr][sk + 8] = src[1];
    }
    __syncthreads();

    half8 af[4], bf[4];
    #pragma unroll
    for (int i = 0; i < 4; ++i) af[i] = *(const half8*)&As[wr*64 + i*16 + fr][fo];
    #pragma unroll
    for (int j = 0; j < 4; ++j) bf[j] = *(const half8*)&Bs[wc*64 + j*16 + fr][fo];
    #pragma unroll
    for (int i = 0; i < 4; ++i)
      #pragma unroll
      for (int j = 0; j < 4; ++j)
        acc[i][j] = __builtin_amdgcn_mfma_f32_16x16x32_f16(af[i], bf[j], acc[i][j], 0, 0, 0);
  }

  const int fq = lane >> 4;
  #pragma unroll
  for (int j = 0; j < 4; ++j) {
    const int col = gn + wc*64 + j*16 + fr;
    const float bj = bias[col];
    #pragma unroll
    for (int i = 0; i < 4; ++i) {
      const int row0 = gm + wr*64 + i*16 + fq*4;
      #pragma unroll
      for (int rr = 0; rr < 4; ++rr) {
        const float v = (acc[i][j][rr] + bj) * scale;
        if (OUT_F16) ((__half*)Outp)[(size_t)(row0 + rr) * 256 + col] = __float2half(v);
        else         ((float*) Outp)[(size_t)(row0 + rr) * 256 + col] = v;
      }
    }
  }
}

// ---------------- gathered local attention ----------------
// One wave per query. lane -> (h = lane>>3, s = lane&7), covers elems col=lane*4..+3
// logits via 4-elem dot + 3x shfl_xor reduce over the 8 lanes of a head.
__global__ __launch_bounds__(256)
void attn_local(const __half* __restrict__ qws, const __half* __restrict__ kws,
                const __half* __restrict__ vws, const int* __restrict__ idxp,
                __half* __restrict__ attn, float* __restrict__ wsum)
{
  const int tid  = threadIdx.x;
  const int lane = tid & 63;
  const int wid  = tid >> 6;
  const int q    = blockIdx.x * 4 + wid;
  const int col  = lane * 4;   // == (lane>>3)*32 + (lane&7)*4

  union U2 { uint2 u; __half h[4]; };

  U2 qu; qu.u = *(const uint2*)(qws + (size_t)q * 256 + col);
  const float q0 = __half2float(qu.h[0]), q1 = __half2float(qu.h[1]),
              q2 = __half2float(qu.h[2]), q3 = __half2float(qu.h[3]);

  int myidx = 0;
  if (lane < 16) myidx = idxp[(size_t)q * 16 + lane];

  float logit[16];
  U2 vk[16];
  #pragma unroll
  for (int n = 0; n < 16; ++n) {
    const int kvi = __shfl(myidx, n);   // wave-uniform
    float p;
    if (kvi >= 0) {
      U2 ku; ku.u = *(const uint2*)(kws + (size_t)kvi * 256 + col);
      vk[n].u     = *(const uint2*)(vws + (size_t)kvi * 256 + col);
      p = q0 * __half2float(ku.h[0]) + q1 * __half2float(ku.h[1])
        + q2 * __half2float(ku.h[2]) + q3 * __half2float(ku.h[3]);
      p += __shfl_xor(p, 1);
      p += __shfl_xor(p, 2);
      p += __shfl_xor(p, 4);
    } else {
      p = -__builtin_inff();
      vk[n].u = make_uint2(0u, 0u);
    }
    logit[n] = p;
  }

  float m = logit[0];
  #pragma unroll
  for (int n = 1; n < 16; ++n) m = fmaxf(m, logit[n]);
  const bool allinv = (m < -1e37f);   // all neighbors invalid

  float w[16]; float ssum = 0.f;
  #pragma unroll
  for (int n = 0; n < 16; ++n) {
    const float e = allinv ? 0.f : __expf(logit[n] - m);
    w[n] = e; ssum += e;
  }
  const float inv = allinv ? 0.f : (1.0f / ssum);

  float a0 = 0.f, a1 = 0.f, a2 = 0.f, a3 = 0.f;
  #pragma unroll
  for (int n = 0; n < 16; ++n) {
    const float wn = w[n] * inv;
    w[n] = wn;
    a0 += wn * __half2float(vk[n].h[0]);
    a1 += wn * __half2float(vk[n].h[1]);
    a2 += wn * __half2float(vk[n].h[2]);
    a3 += wn * __half2float(vk[n].h[3]);
  }

  U2 o; o.h[0] = __float2half(a0); o.h[1] = __float2half(a1);
        o.h[2] = __float2half(a2); o.h[3] = __float2half(a3);
  *(uint2*)(attn + (size_t)q * 256 + col) = o.u;

  // weights_sum[q][n] = (sum_h w[n,h]) / 8 ; heads live at lane strides of 8
  float wsr = 0.f;
  #pragma unroll
  for (int n = 0; n < 16; ++n) {
    float t = w[n];
    t += __shfl_xor(t, 8);
    t += __shfl_xor(t, 16);
    t += __shfl_xor(t, 32);
    if (lane == n) wsr = t;
  }
  if (lane < 16) wsum[(size_t)q * 16 + lane] = wsr * 0.125f;
}

// ---------------- launch ----------------
extern "C" void kernel_launch(void* const* d_in, const int* in_sizes, int n_in,
                              void* d_out, int out_size, void* d_ws, size_t ws_size,
                              hipStream_t stream)
{
  const float* query = (const float*)d_in[0];
  const float* key   = (const float*)d_in[1];
  const float* value = (const float*)d_in[2];
  const int*   idxp  = (const int*)  d_in[3];
  const float* wqkv  = (const float*)d_in[4];
  const float* bqkv  = (const float*)d_in[5];
  const float* wout  = (const float*)d_in[6];
  const float* bout  = (const float*)d_in[7];
  float* out = (float*)d_out;

  char* ws   = (char*)d_ws;
  __half* Wh = (__half*)(ws + WQKV_OFF);   // 768x256 then 256x256 contiguous
  __half* qh = (__half*)(ws + Q_OFF);
  __half* kh = (__half*)(ws + K_OFF);
  __half* vh = (__half*)(ws + V_OFF);
  __half* ah = (__half*)(ws + A_OFF);

  // convert weights to f16 (262144 elems / 4 per thread = 65536 threads)
  prep_weights<<<256, 256, 0, stream>>>(wqkv, wout, Wh);

  dim3 ggrid(QLEN / 128, 2);
  const float qscale = 0.17677669529663687f;  // 1/sqrt(32)
  gemm_e256<true,  true ><<<ggrid, 256, 0, stream>>>(query, Wh,             bqkv,       qscale, qh);
  gemm_e256<true,  true ><<<ggrid, 256, 0, stream>>>(key,   Wh + 256*256,   bqkv + 256, 1.0f,   kh);
  gemm_e256<true,  true ><<<ggrid, 256, 0, stream>>>(value, Wh + 512*256,   bqkv + 512, 1.0f,   vh);

  attn_local<<<QLEN / 4, 256, 0, stream>>>(qh, kh, vh, idxp, ah, out + (size_t)QLEN * EDIM);

  gemm_e256<false, false><<<ggrid, 256, 0, stream>>>(ah, Wh + 768*256, bout, 1.0f, out);
}

// Round 2
// 452.067 us; speedup vs baseline: 1.0888x; 1.0888x over previous
//
#include <hip/hip_runtime.h>
#include <hip/hip_fp16.h>

#define QLEN   65536
#define EDIM   256

typedef _Float16 half8 __attribute__((ext_vector_type(8)));
typedef float    f32x4 __attribute__((ext_vector_type(4)));

// ---------------- workspace layout (bytes) ----------------
static const size_t WQKV_OFF = 0;
static const size_t WOUT_OFF = 768u * 256u * 2u;                 // 393216
static const size_t Q_OFF    = WOUT_OFF + 256u * 256u * 2u;      // 524288
static const size_t K_OFF    = Q_OFF + (size_t)QLEN * EDIM * 2u;
static const size_t V_OFF    = K_OFF + (size_t)QLEN * EDIM * 2u;
static const size_t A_OFF    = V_OFF + (size_t)QLEN * EDIM * 2u; // end ~134.7MB

// ---------------- weight f32 -> f16 conversion ----------------
__global__ void prep_weights(const float* __restrict__ wqkv,
                             const float* __restrict__ wout,
                             __half* __restrict__ dst)
{
  int g = (blockIdx.x * blockDim.x + threadIdx.x) * 4;
  float4 f;
  if (g < 768 * 256) f = *(const float4*)(wqkv + g);
  else               f = *(const float4*)(wout + (g - 768 * 256));
  union { __half h[4]; uint2 u; } c;
  c.h[0] = __float2half(f.x); c.h[1] = __float2half(f.y);
  c.h[2] = __float2half(f.z); c.h[3] = __float2half(f.w);
  *(uint2*)(dst + g) = c.u;
}

// ---------------- GEMM v2: Out[m][n] = (sum_k A[m][k]*W[n][k] + bias[n]) * scale
// BM=128, BN=256 (full N -> A read once), K=256, BK=32, 8 chunks.
// 512 threads = 8 waves in 2x4; wave owns 64x64 = 4x4 tiles of 16x16.
// Double-buffered padded LDS; next-chunk global loads issued before the
// barrier+MFMA of the current chunk (T14 split), cvt+ds_write after MFMA.
// blockIdx.y in {0,1,2} selects q/k/v (A ptr, W row block, bias block, scale).
template<bool A_F32, bool OUT_F16>
__global__ __launch_bounds__(512)
void gemm_e256v2(const void* __restrict__ A0, const void* __restrict__ A1,
                 const void* __restrict__ A2,
                 const __half* __restrict__ Wbase, const float* __restrict__ bias,
                 float scale0,
                 void* __restrict__ O0, void* __restrict__ O1, void* __restrict__ O2)
{
  __shared__ __half As[2][128][40];   // 20 KB
  __shared__ __half Bs[2][256][40];   // 40 KB

  const int y = blockIdx.y;
  const void* Ain  = (y == 0) ? A0 : (y == 1) ? A1 : A2;
  void*       Outp = (y == 0) ? O0 : (y == 1) ? O1 : O2;
  const __half* W  = Wbase + (size_t)y * 256 * 256;
  const float* bp  = bias + y * 256;
  const float scale = (y == 0) ? scale0 : 1.0f;

  const int tid  = threadIdx.x;
  const int lane = tid & 63;
  const int wid  = tid >> 6;
  const int wr   = wid >> 2;        // 0..1 (row half)
  const int wc   = wid & 3;         // 0..3 (col quarter)
  const int gm   = blockIdx.x * 128;

  // staging maps
  const int ar = tid >> 2, ac = (tid & 3) * 8;    // A: 128 rows x 32, 8 elems/thread
  const int br = tid >> 1, bc = (tid & 1) * 16;   // B: 256 rows x 32, 16 halfs/thread

  // fragment maps
  const int fr = lane & 15;
  const int fo = (lane >> 4) * 8;
  const int fq = lane >> 4;

  f32x4 acc[4][4] = {};

  // register staging buffers for next chunk
  float4 ra0, ra1;   // A f32 path
  uint4  ua;         // A f16 path
  uint4  rb0, rb1;   // B halfs

  // ---- prologue: load + write chunk 0 into buf 0 ----
  if (A_F32) {
    const float* src = (const float*)Ain + (size_t)(gm + ar) * 256 + ac;
    ra0 = ((const float4*)src)[0];
    ra1 = ((const float4*)src)[1];
    union { __half h[8]; uint4 u; } t;
    t.h[0]=__float2half(ra0.x); t.h[1]=__float2half(ra0.y);
    t.h[2]=__float2half(ra0.z); t.h[3]=__float2half(ra0.w);
    t.h[4]=__float2half(ra1.x); t.h[5]=__float2half(ra1.y);
    t.h[6]=__float2half(ra1.z); t.h[7]=__float2half(ra1.w);
    *(uint4*)&As[0][ar][ac] = t.u;
  } else {
    const __half* src = (const __half*)Ain + (size_t)(gm + ar) * 256 + ac;
    *(uint4*)&As[0][ar][ac] = *(const uint4*)src;
  }
  {
    const __half* src = W + (size_t)br * 256 + bc;
    *(uint4*)&Bs[0][br][bc]     = ((const uint4*)src)[0];
    *(uint4*)&Bs[0][br][bc + 8] = ((const uint4*)src)[1];
  }

  int cur = 0;
  #pragma unroll
  for (int kc = 0; kc < 8; ++kc, cur ^= 1) {
    // issue next-chunk global loads (hidden under barrier + MFMA)
    if (kc < 7) {
      if (A_F32) {
        const float* src = (const float*)Ain + (size_t)(gm + ar) * 256 + (kc + 1) * 32 + ac;
        ra0 = ((const float4*)src)[0];
        ra1 = ((const float4*)src)[1];
      } else {
        const __half* src = (const __half*)Ain + (size_t)(gm + ar) * 256 + (kc + 1) * 32 + ac;
        ua = *(const uint4*)src;
      }
      const __half* src = W + (size_t)br * 256 + (kc + 1) * 32 + bc;
      rb0 = ((const uint4*)src)[0];
      rb1 = ((const uint4*)src)[1];
    }

    __syncthreads();   // buf[cur] writes visible

    half8 af[4], bf[4];
    #pragma unroll
    for (int i = 0; i < 4; ++i) af[i] = *(const half8*)&As[cur][wr*64 + i*16 + fr][fo];
    #pragma unroll
    for (int j = 0; j < 4; ++j) bf[j] = *(const half8*)&Bs[cur][wc*64 + j*16 + fr][fo];
    #pragma unroll
    for (int i = 0; i < 4; ++i)
      #pragma unroll
      for (int j = 0; j < 4; ++j)
        acc[i][j] = __builtin_amdgcn_mfma_f32_16x16x32_f16(af[i], bf[j], acc[i][j], 0, 0, 0);

    // stage next chunk into the other buffer
    if (kc < 7) {
      if (A_F32) {
        union { __half h[8]; uint4 u; } t;
        t.h[0]=__float2half(ra0.x); t.h[1]=__float2half(ra0.y);
        t.h[2]=__float2half(ra0.z); t.h[3]=__float2half(ra0.w);
        t.h[4]=__float2half(ra1.x); t.h[5]=__float2half(ra1.y);
        t.h[6]=__float2half(ra1.z); t.h[7]=__float2half(ra1.w);
        *(uint4*)&As[cur ^ 1][ar][ac] = t.u;
      } else {
        *(uint4*)&As[cur ^ 1][ar][ac] = ua;
      }
      *(uint4*)&Bs[cur ^ 1][br][bc]     = rb0;
      *(uint4*)&Bs[cur ^ 1][br][bc + 8] = rb1;
    }
  }

  // ---- epilogue ----
  #pragma unroll
  for (int j = 0; j < 4; ++j) {
    const int col = wc*64 + j*16 + fr;
    const float bj = bp[col];
    #pragma unroll
    for (int i = 0; i < 4; ++i) {
      const int row0 = gm + wr*64 + i*16 + fq*4;
      #pragma unroll
      for (int rr = 0; rr < 4; ++rr) {
        const float v = (acc[i][j][rr] + bj) * scale;
        if (OUT_F16) ((__half*)Outp)[(size_t)(row0 + rr) * 256 + col] = __float2half(v);
        else         ((float*) Outp)[(size_t)(row0 + rr) * 256 + col] = v;
      }
    }
  }
}

// ---------------- gathered local attention (unchanged from round 1) ----------
__global__ __launch_bounds__(256)
void attn_local(const __half* __restrict__ qws, const __half* __restrict__ kws,
                const __half* __restrict__ vws, const int* __restrict__ idxp,
                __half* __restrict__ attn, float* __restrict__ wsum)
{
  const int tid  = threadIdx.x;
  const int lane = tid & 63;
  const int wid  = tid >> 6;
  const int q    = blockIdx.x * 4 + wid;
  const int col  = lane * 4;

  union U2 { uint2 u; __half h[4]; };

  U2 qu; qu.u = *(const uint2*)(qws + (size_t)q * 256 + col);
  const float q0 = __half2float(qu.h[0]), q1 = __half2float(qu.h[1]),
              q2 = __half2float(qu.h[2]), q3 = __half2float(qu.h[3]);

  int myidx = 0;
  if (lane < 16) myidx = idxp[(size_t)q * 16 + lane];

  float logit[16];
  U2 vk[16];
  #pragma unroll
  for (int n = 0; n < 16; ++n) {
    const int kvi = __shfl(myidx, n);
    float p;
    if (kvi >= 0) {
      U2 ku; ku.u = *(const uint2*)(kws + (size_t)kvi * 256 + col);
      vk[n].u     = *(const uint2*)(vws + (size_t)kvi * 256 + col);
      p = q0 * __half2float(ku.h[0]) + q1 * __half2float(ku.h[1])
        + q2 * __half2float(ku.h[2]) + q3 * __half2float(ku.h[3]);
      p += __shfl_xor(p, 1);
      p += __shfl_xor(p, 2);
      p += __shfl_xor(p, 4);
    } else {
      p = -__builtin_inff();
      vk[n].u = make_uint2(0u, 0u);
    }
    logit[n] = p;
  }

  float m = logit[0];
  #pragma unroll
  for (int n = 1; n < 16; ++n) m = fmaxf(m, logit[n]);
  const bool allinv = (m < -1e37f);

  float w[16]; float ssum = 0.f;
  #pragma unroll
  for (int n = 0; n < 16; ++n) {
    const float e = allinv ? 0.f : __expf(logit[n] - m);
    w[n] = e; ssum += e;
  }
  const float inv = allinv ? 0.f : (1.0f / ssum);

  float a0 = 0.f, a1 = 0.f, a2 = 0.f, a3 = 0.f;
  #pragma unroll
  for (int n = 0; n < 16; ++n) {
    const float wn = w[n] * inv;
    w[n] = wn;
    a0 += wn * __half2float(vk[n].h[0]);
    a1 += wn * __half2float(vk[n].h[1]);
    a2 += wn * __half2float(vk[n].h[2]);
    a3 += wn * __half2float(vk[n].h[3]);
  }

  U2 o; o.h[0] = __float2half(a0); o.h[1] = __float2half(a1);
        o.h[2] = __float2half(a2); o.h[3] = __float2half(a3);
  *(uint2*)(attn + (size_t)q * 256 + col) = o.u;

  float wsr = 0.f;
  #pragma unroll
  for (int n = 0; n < 16; ++n) {
    float t = w[n];
    t += __shfl_xor(t, 8);
    t += __shfl_xor(t, 16);
    t += __shfl_xor(t, 32);
    if (lane == n) wsr = t;
  }
  if (lane < 16) wsum[(size_t)q * 16 + lane] = wsr * 0.125f;
}

// ---------------- launch ----------------
extern "C" void kernel_launch(void* const* d_in, const int* in_sizes, int n_in,
                              void* d_out, int out_size, void* d_ws, size_t ws_size,
                              hipStream_t stream)
{
  const float* query = (const float*)d_in[0];
  const float* key   = (const float*)d_in[1];
  const float* value = (const float*)d_in[2];
  const int*   idxp  = (const int*)  d_in[3];
  const float* wqkv  = (const float*)d_in[4];
  const float* bqkv  = (const float*)d_in[5];
  const float* wout  = (const float*)d_in[6];
  const float* bout  = (const float*)d_in[7];
  float* out = (float*)d_out;

  char* ws   = (char*)d_ws;
  __half* Wh = (__half*)(ws + WQKV_OFF);
  __half* qh = (__half*)(ws + Q_OFF);
  __half* kh = (__half*)(ws + K_OFF);
  __half* vh = (__half*)(ws + V_OFF);
  __half* ah = (__half*)(ws + A_OFF);

  prep_weights<<<256, 256, 0, stream>>>(wqkv, wout, Wh);

  const float qscale = 0.17677669529663687f;  // 1/sqrt(32)

  // fused q/k/v projections: grid.y selects which
  gemm_e256v2<true, true><<<dim3(QLEN / 128, 3), 512, 0, stream>>>(
      query, key, value, Wh, bqkv, qscale, qh, kh, vh);

  attn_local<<<QLEN / 4, 256, 0, stream>>>(qh, kh, vh, idxp, ah, out + (size_t)QLEN * EDIM);

  // out projection (A = attn f16, out f32)
  gemm_e256v2<false, false><<<dim3(QLEN / 128, 1), 512, 0, stream>>>(
      ah, ah, ah, Wh + 768 * 256, bout, 1.0f, out, out, out);
}

// Round 3
// 429.716 us; speedup vs baseline: 1.1454x; 1.0520x over previous
//
#include <hip/hip_runtime.h>
#include <hip/hip_fp16.h>

#define QLEN   65536
#define EDIM   256

typedef _Float16 half8 __attribute__((ext_vector_type(8)));
typedef float    f32x4 __attribute__((ext_vector_type(4)));

// ---------------- workspace layout (bytes) ----------------
static const size_t WQKV_OFF = 0;
static const size_t WOUT_OFF = 768u * 256u * 2u;                 // 393216
static const size_t Q_OFF    = WOUT_OFF + 256u * 256u * 2u;      // 524288
static const size_t K_OFF    = Q_OFF + (size_t)QLEN * EDIM * 2u;
static const size_t V_OFF    = K_OFF + (size_t)QLEN * EDIM * 2u;
static const size_t A_OFF    = V_OFF + (size_t)QLEN * EDIM * 2u; // end ~134.7MB

// ---------------- weight f32 -> f16 conversion ----------------
__global__ void prep_weights(const float* __restrict__ wqkv,
                             const float* __restrict__ wout,
                             __half* __restrict__ dst)
{
  int g = (blockIdx.x * blockDim.x + threadIdx.x) * 4;
  float4 f;
  if (g < 768 * 256) f = *(const float4*)(wqkv + g);
  else               f = *(const float4*)(wout + (g - 768 * 256));
  union { __half h[4]; uint2 u; } c;
  c.h[0] = __float2half(f.x); c.h[1] = __float2half(f.y);
  c.h[2] = __float2half(f.z); c.h[3] = __float2half(f.w);
  *(uint2*)(dst + g) = c.u;
}

// ---------------- GEMM v2 (unchanged from round 2) ----------------
template<bool A_F32, bool OUT_F16>
__global__ __launch_bounds__(512)
void gemm_e256v2(const void* __restrict__ A0, const void* __restrict__ A1,
                 const void* __restrict__ A2,
                 const __half* __restrict__ Wbase, const float* __restrict__ bias,
                 float scale0,
                 void* __restrict__ O0, void* __restrict__ O1, void* __restrict__ O2)
{
  __shared__ __half As[2][128][40];
  __shared__ __half Bs[2][256][40];

  const int y = blockIdx.y;
  const void* Ain  = (y == 0) ? A0 : (y == 1) ? A1 : A2;
  void*       Outp = (y == 0) ? O0 : (y == 1) ? O1 : O2;
  const __half* W  = Wbase + (size_t)y * 256 * 256;
  const float* bp  = bias + y * 256;
  const float scale = (y == 0) ? scale0 : 1.0f;

  const int tid  = threadIdx.x;
  const int lane = tid & 63;
  const int wid  = tid >> 6;
  const int wr   = wid >> 2;
  const int wc   = wid & 3;
  const int gm   = blockIdx.x * 128;

  const int ar = tid >> 2, ac = (tid & 3) * 8;
  const int br = tid >> 1, bc = (tid & 1) * 16;

  const int fr = lane & 15;
  const int fo = (lane >> 4) * 8;
  const int fq = lane >> 4;

  f32x4 acc[4][4] = {};

  float4 ra0, ra1;
  uint4  ua;
  uint4  rb0, rb1;

  if (A_F32) {
    const float* src = (const float*)Ain + (size_t)(gm + ar) * 256 + ac;
    ra0 = ((const float4*)src)[0];
    ra1 = ((const float4*)src)[1];
    union { __half h[8]; uint4 u; } t;
    t.h[0]=__float2half(ra0.x); t.h[1]=__float2half(ra0.y);
    t.h[2]=__float2half(ra0.z); t.h[3]=__float2half(ra0.w);
    t.h[4]=__float2half(ra1.x); t.h[5]=__float2half(ra1.y);
    t.h[6]=__float2half(ra1.z); t.h[7]=__float2half(ra1.w);
    *(uint4*)&As[0][ar][ac] = t.u;
  } else {
    const __half* src = (const __half*)Ain + (size_t)(gm + ar) * 256 + ac;
    *(uint4*)&As[0][ar][ac] = *(const uint4*)src;
  }
  {
    const __half* src = W + (size_t)br * 256 + bc;
    *(uint4*)&Bs[0][br][bc]     = ((const uint4*)src)[0];
    *(uint4*)&Bs[0][br][bc + 8] = ((const uint4*)src)[1];
  }

  int cur = 0;
  #pragma unroll
  for (int kc = 0; kc < 8; ++kc, cur ^= 1) {
    if (kc < 7) {
      if (A_F32) {
        const float* src = (const float*)Ain + (size_t)(gm + ar) * 256 + (kc + 1) * 32 + ac;
        ra0 = ((const float4*)src)[0];
        ra1 = ((const float4*)src)[1];
      } else {
        const __half* src = (const __half*)Ain + (size_t)(gm + ar) * 256 + (kc + 1) * 32 + ac;
        ua = *(const uint4*)src;
      }
      const __half* src = W + (size_t)br * 256 + (kc + 1) * 32 + bc;
      rb0 = ((const uint4*)src)[0];
      rb1 = ((const uint4*)src)[1];
    }

    __syncthreads();

    half8 af[4], bf[4];
    #pragma unroll
    for (int i = 0; i < 4; ++i) af[i] = *(const half8*)&As[cur][wr*64 + i*16 + fr][fo];
    #pragma unroll
    for (int j = 0; j < 4; ++j) bf[j] = *(const half8*)&Bs[cur][wc*64 + j*16 + fr][fo];
    #pragma unroll
    for (int i = 0; i < 4; ++i)
      #pragma unroll
      for (int j = 0; j < 4; ++j)
        acc[i][j] = __builtin_amdgcn_mfma_f32_16x16x32_f16(af[i], bf[j], acc[i][j], 0, 0, 0);

    if (kc < 7) {
      if (A_F32) {
        union { __half h[8]; uint4 u; } t;
        t.h[0]=__float2half(ra0.x); t.h[1]=__float2half(ra0.y);
        t.h[2]=__float2half(ra0.z); t.h[3]=__float2half(ra0.w);
        t.h[4]=__float2half(ra1.x); t.h[5]=__float2half(ra1.y);
        t.h[6]=__float2half(ra1.z); t.h[7]=__float2half(ra1.w);
        *(uint4*)&As[cur ^ 1][ar][ac] = t.u;
      } else {
        *(uint4*)&As[cur ^ 1][ar][ac] = ua;
      }
      *(uint4*)&Bs[cur ^ 1][br][bc]     = rb0;
      *(uint4*)&Bs[cur ^ 1][br][bc + 8] = rb1;
    }
  }

  #pragma unroll
  for (int j = 0; j < 4; ++j) {
    const int col = wc*64 + j*16 + fr;
    const float bj = bp[col];
    #pragma unroll
    for (int i = 0; i < 4; ++i) {
      const int row0 = gm + wr*64 + i*16 + fq*4;
      #pragma unroll
      for (int rr = 0; rr < 4; ++rr) {
        const float v = (acc[i][j][rr] + bj) * scale;
        if (OUT_F16) ((__half*)Outp)[(size_t)(row0 + rr) * 256 + col] = __float2half(v);
        else         ((float*) Outp)[(size_t)(row0 + rr) * 256 + col] = v;
      }
    }
  }
}

// ---------------- gathered local attention v2 ----------------
// One wave per query iteration, QPW queries per wave.
// Lane split: half = lane>>5 handles neighbors n = 2j+half (j=0..7);
// within a half, lane covers 8 dims at col=(lane&31)*8 (head = (lane&31)>>2).
// 8 K + 8 V dwordx4 gathers per query, all issued before compute.
#define QPW 4
__global__ __launch_bounds__(256)
void attn_local2(const __half* __restrict__ qws, const __half* __restrict__ kws,
                 const __half* __restrict__ vws, const int* __restrict__ idxp,
                 __half* __restrict__ attn, float* __restrict__ wsum)
{
  const int tid  = threadIdx.x;
  const int lane = tid & 63;
  const int wid  = tid >> 6;
  const int l31  = lane & 31;
  const int half = lane >> 5;
  const int col  = l31 * 8;

  const int q0 = (blockIdx.x * 4 + wid) * QPW;

  union U4 { uint4 u; __half h[8]; };

  for (int it = 0; it < QPW; ++it) {
    const int q = q0 + it;

    int myidx = 0;
    if (lane < 16) myidx = idxp[(size_t)q * 16 + lane];

    U4 qu; qu.u = *(const uint4*)(qws + (size_t)q * 256 + col);

    // ---- issue all gathers up-front ----
    int kvi[8];
    U4 ku[8], vu[8];
    #pragma unroll
    for (int j = 0; j < 8; ++j) {
      kvi[j] = __shfl(myidx, 2 * j + half);
      const size_t s = (size_t)(kvi[j] < 0 ? 0 : kvi[j]) * 256;
      ku[j].u = *(const uint4*)(kws + s + col);
    }
    #pragma unroll
    for (int j = 0; j < 8; ++j) {
      const size_t s = (size_t)(kvi[j] < 0 ? 0 : kvi[j]) * 256;
      vu[j].u = *(const uint4*)(vws + s + col);
    }

    float qf[8];
    #pragma unroll
    for (int e = 0; e < 8; ++e) qf[e] = __half2float(qu.h[e]);

    // ---- logits: 8-elem dot + 2 shfl_xor (4-lane head group) ----
    float logit[8];
    #pragma unroll
    for (int j = 0; j < 8; ++j) {
      float p = 0.f;
      #pragma unroll
      for (int e = 0; e < 8; ++e) p += qf[e] * __half2float(ku[j].h[e]);
      p += __shfl_xor(p, 1);
      p += __shfl_xor(p, 2);
      logit[j] = (kvi[j] < 0) ? -__builtin_inff() : p;
    }

    // ---- per-head softmax over 16 neighbors (merge halves via xor 32) ----
    float m = logit[0];
    #pragma unroll
    for (int j = 1; j < 8; ++j) m = fmaxf(m, logit[j]);
    m = fmaxf(m, __shfl_xor(m, 32));
    const bool allinv = (m < -1e37f);

    float w[8]; float s8 = 0.f;
    #pragma unroll
    for (int j = 0; j < 8; ++j) {
      const float e = allinv ? 0.f : __expf(logit[j] - m);
      w[j] = e; s8 += e;
    }
    const float s = s8 + __shfl_xor(s8, 32);
    const float inv = allinv ? 0.f : (1.0f / s);

    // ---- weighted V accumulate ----
    float acc[8] = {};
    #pragma unroll
    for (int j = 0; j < 8; ++j) {
      const float wn = w[j] * inv;
      w[j] = wn;
      #pragma unroll
      for (int e = 0; e < 8; ++e) acc[e] += wn * __half2float(vu[j].h[e]);
    }

    // merge halves, lanes 0-31 write 16B coalesced
    #pragma unroll
    for (int e = 0; e < 8; ++e) acc[e] += __shfl_xor(acc[e], 32);
    if (half == 0) {
      U4 o;
      #pragma unroll
      for (int e = 0; e < 8; ++e) o.h[e] = __float2half(acc[e]);
      *(uint4*)(attn + (size_t)q * 256 + col) = o.u;
    }

    // ---- weights_sum: reduce w[j] over heads (xor 4,8,16 within half) ----
    #pragma unroll
    for (int j = 0; j < 8; ++j) {
      float t = w[j];
      t += __shfl_xor(t, 4);
      t += __shfl_xor(t, 8);
      t += __shfl_xor(t, 16);
      if (l31 == j) wsum[(size_t)q * 16 + 2 * j + half] = t * 0.125f;
    }
  }
}

// ---------------- launch ----------------
extern "C" void kernel_launch(void* const* d_in, const int* in_sizes, int n_in,
                              void* d_out, int out_size, void* d_ws, size_t ws_size,
                              hipStream_t stream)
{
  const float* query = (const float*)d_in[0];
  const float* key   = (const float*)d_in[1];
  const float* value = (const float*)d_in[2];
  const int*   idxp  = (const int*)  d_in[3];
  const float* wqkv  = (const float*)d_in[4];
  const float* bqkv  = (const float*)d_in[5];
  const float* wout  = (const float*)d_in[6];
  const float* bout  = (const float*)d_in[7];
  float* out = (float*)d_out;

  char* ws   = (char*)d_ws;
  __half* Wh = (__half*)(ws + WQKV_OFF);
  __half* qh = (__half*)(ws + Q_OFF);
  __half* kh = (__half*)(ws + K_OFF);
  __half* vh = (__half*)(ws + V_OFF);
  __half* ah = (__half*)(ws + A_OFF);

  prep_weights<<<256, 256, 0, stream>>>(wqkv, wout, Wh);

  const float qscale = 0.17677669529663687f;  // 1/sqrt(32)

  gemm_e256v2<true, true><<<dim3(QLEN / 128, 3), 512, 0, stream>>>(
      query, key, value, Wh, bqkv, qscale, qh, kh, vh);

  attn_local2<<<QLEN / 4 / QPW, 256, 0, stream>>>(qh, kh, vh, idxp, ah,
                                                  out + (size_t)QLEN * EDIM);

  gemm_e256v2<false, false><<<dim3(QLEN / 128, 1), 512, 0, stream>>>(
      ah, ah, ah, Wh + 768 * 256, bout, 1.0f, out, out, out);
}